// Round 1
// baseline (780.162 us; speedup 1.0000x reference)
//
#include <hip/hip_runtime.h>
#include <cstdint>

// Problem: B=32, N=4096, C=768, H=12, hd=64, L=32, chunk=24
// Identity: out[b,l,c'] = (sum_n attn[b,l,n] x[b,n,:]) . v_w[l*24+c',:] + v_b
// Pipeline (x read once in f32, once in bf16-transposed form):
//   k0:  qbf = bf16(latent * 0.125)  [h][l][64], 48 KB (L2-resident)
//   K1:  per (b, 64-row n-tile): S = qbf . k via MFMA; E=exp(S) -> bf16;
//        ALSO writes xT[b][c][n] bf16 (201 MB) via LDS transpose.
//   KW:  per (b,l): sums_h = sum_n E; W[b,l,n] = sum_h E/(12*sums_h) (bf16)
//   K3:  y[g][b,l,c] = sum_{n in g} W[b,l,n]*x[b,n,c]  (MFMA, xT vectorized)
//   K4:  out = (sum_g y) . v_w^T + v_b

typedef short bf16x8 __attribute__((ext_vector_type(8)));
typedef float f32x4 __attribute__((ext_vector_type(4)));

#define MFMA16(a, b, c) __builtin_amdgcn_mfma_f32_16x16x32_bf16((a), (b), (c), 0, 0, 0)

// pack two f32 -> (bf16(a) | bf16(b)<<16) by byte-select (truncation, 1 VALU)
__device__ __forceinline__ uint32_t pk_bf16(float a, float b) {
    return __builtin_amdgcn_perm(__float_as_uint(b), __float_as_uint(a), 0x07060302u);
}
__device__ __forceinline__ unsigned short bf16_trunc(float f) {
    return (unsigned short)(__float_as_uint(f) >> 16);
}
__device__ __forceinline__ float bf16_lo(uint32_t u) { return __uint_as_float(u << 16); }
__device__ __forceinline__ float bf16_hi(uint32_t u) { return __uint_as_float(u & 0xffff0000u); }

// ---------------------------------------------------------------------------
// k0: qbf[h][l][d] = bf16(latent[l][h*64+d] * 0.125)   (24576 elems)
// ---------------------------------------------------------------------------
__global__ __launch_bounds__(256)
void k0_qconv(const float* __restrict__ latent, unsigned short* __restrict__ qbf)
{
    int i = blockIdx.x * 256 + threadIdx.x;       // 0..24575
    int l = i / 768;
    int r = i - l * 768;
    int h = r >> 6, d = r & 63;
    qbf[(h * 32 + l) * 64 + d] = bf16_trunc(latent[i] * 0.125f);
}

// ---------------------------------------------------------------------------
// K1: per (b, 64-row n-tile): for each h, S[l][n] = qbf . k via MFMA
// 16x16x32 (A[m=lane&15][k=quad*8+j], B[k][n=lane&15], D col=lane&15,
// row=quad*4+reg), E = exp(S) stored bf16 at E[((b*12+h)*32+l)*4096+n].
// Also writes xT[b][h*64+d][n0..n0+64] bf16 from the staged LDS tile.
// grid = 32*64 = 2048 blocks x 256.
// ---------------------------------------------------------------------------
__global__ __launch_bounds__(256)
void k1_logits(const float* __restrict__ x, const unsigned short* __restrict__ qbf,
               unsigned short* __restrict__ E, unsigned short* __restrict__ xT)
{
    const int b   = blockIdx.x >> 6;
    const int n0  = (blockIdx.x & 63) << 6;
    const int tid = threadIdx.x;
    const int wv  = tid >> 6;
    const int lane = tid & 63;
    const int quad = lane >> 4;
    const int lc   = lane & 15;

    __shared__ unsigned short x_lds[64][72];   // +8 pad: frag reads 2-way (free)

    const int n = n0 + wv * 16 + lc;
    const int td = lane;   // transpose-write: lanes sweep d (conflict-free LDS reads)

    for (int h = 0; h < 12; ++h) {
        __syncthreads();
        // stage x head-slice: 64 n x 64 d, f32 -> bf16
        for (int i = tid; i < 1024; i += 256) {
            int nn = i >> 4, f4 = i & 15;
            float4 xv = *(const float4*)&x[(size_t)(b * 4096 + n0 + nn) * 768 + h * 64 + f4 * 4];
            uint2 p;
            p.x = pk_bf16(xv.x, xv.y);
            p.y = pk_bf16(xv.z, xv.w);
            *(uint2*)&x_lds[nn][f4 * 4] = p;
        }
        __syncthreads();

        // A-frags straight from global qbf (L1/L2-hot, 4 KB per h)
        const unsigned short* qh = qbf + h * 2048;
        bf16x8 a00 = *(const bf16x8*)&qh[lc * 64 + quad * 8];
        bf16x8 a01 = *(const bf16x8*)&qh[lc * 64 + 32 + quad * 8];
        bf16x8 a10 = *(const bf16x8*)&qh[(16 + lc) * 64 + quad * 8];
        bf16x8 a11 = *(const bf16x8*)&qh[(16 + lc) * 64 + 32 + quad * 8];
        bf16x8 b0  = *(const bf16x8*)&x_lds[wv * 16 + lc][quad * 8];
        bf16x8 b1  = *(const bf16x8*)&x_lds[wv * 16 + lc][32 + quad * 8];

        f32x4 c0 = {0.f, 0.f, 0.f, 0.f};
        f32x4 c1 = {0.f, 0.f, 0.f, 0.f};
        c0 = MFMA16(a00, b0, c0);
        c0 = MFMA16(a01, b1, c0);
        c1 = MFMA16(a10, b0, c1);
        c1 = MFMA16(a11, b1, c1);

        unsigned short* Eh = E + (size_t)((b * 12 + h) * 32) * 4096;
        #pragma unroll
        for (int r = 0; r < 4; ++r) {
            // |S| <~ 0.2: exp without max-subtraction is exact softmax math
            Eh[(quad * 4 + r) * 4096 + n]      = bf16_trunc(__expf(c0[r]));
            Eh[(16 + quad * 4 + r) * 4096 + n] = bf16_trunc(__expf(c1[r]));
        }

        // xT write: row = b*768 + h*64 + td, cols n0..n0+64.
        // LDS read x_lds[row][td]: dword index = row*36 + td/2 -> across 64
        // lanes td/2 hits all 32 banks, even/odd td share a dword (broadcast).
        unsigned short* xTrow = xT + ((size_t)b * 768 + h * 64 + td) * 4096 + n0;
        #pragma unroll
        for (int half = 0; half < 2; ++half) {
            const int nc = wv + half * 4;      // n-chunk of 8
            unsigned short r0 = x_lds[nc * 8 + 0][td], r1 = x_lds[nc * 8 + 1][td];
            unsigned short r2 = x_lds[nc * 8 + 2][td], r3 = x_lds[nc * 8 + 3][td];
            unsigned short r4 = x_lds[nc * 8 + 4][td], r5 = x_lds[nc * 8 + 5][td];
            unsigned short r6 = x_lds[nc * 8 + 6][td], r7 = x_lds[nc * 8 + 7][td];
            uint4 w;
            w.x = (uint32_t)r0 | ((uint32_t)r1 << 16);
            w.y = (uint32_t)r2 | ((uint32_t)r3 << 16);
            w.z = (uint32_t)r4 | ((uint32_t)r5 << 16);
            w.w = (uint32_t)r6 | ((uint32_t)r7 << 16);
            *(uint4*)&xTrow[nc * 8] = w;
        }
    }
}

// ---------------------------------------------------------------------------
// KW: block = (b,l), 256 thr. Phase 1: sums[h] = sum_n E[b,h,l,n].
// Phase 2: W[b,l,n] = sum_h E * 1/(12*sums[h]). Second E read is L2-hot
// (96 KB/block). No atomics anywhere.
// ---------------------------------------------------------------------------
__global__ __launch_bounds__(256)
void kw_weights(const unsigned short* __restrict__ E, unsigned short* __restrict__ W)
{
    const int b = blockIdx.x >> 5;
    const int l = blockIdx.x & 31;
    const int tid = threadIdx.x;
    const int wv = tid >> 6, lane = tid & 63;

    const unsigned short* Eb = E + (size_t)(b * 384 + l) * 4096;  // +h*32*4096
    __shared__ float red[12][4];
    __shared__ float rsl[12];

    float s[12];
    #pragma unroll
    for (int h = 0; h < 12; ++h) {
        const uint4* p = (const uint4*)(Eb + (size_t)h * 131072 + tid * 16);
        uint4 u0 = p[0], u1 = p[1];
        float v = 0.f;
        v += bf16_lo(u0.x) + bf16_hi(u0.x) + bf16_lo(u0.y) + bf16_hi(u0.y);
        v += bf16_lo(u0.z) + bf16_hi(u0.z) + bf16_lo(u0.w) + bf16_hi(u0.w);
        v += bf16_lo(u1.x) + bf16_hi(u1.x) + bf16_lo(u1.y) + bf16_hi(u1.y);
        v += bf16_lo(u1.z) + bf16_hi(u1.z) + bf16_lo(u1.w) + bf16_hi(u1.w);
        #pragma unroll
        for (int m = 1; m < 64; m <<= 1) v += __shfl_xor(v, m);
        s[h] = v;
    }
    if (lane == 0) {
        #pragma unroll
        for (int h = 0; h < 12; ++h) red[h][wv] = s[h];
    }
    __syncthreads();
    if (tid < 12) rsl[tid] = 1.0f / (12.0f * (red[tid][0] + red[tid][1] + red[tid][2] + red[tid][3]));
    __syncthreads();

    float acc[16];
    #pragma unroll
    for (int i = 0; i < 16; ++i) acc[i] = 0.f;
    #pragma unroll
    for (int h = 0; h < 12; ++h) {
        float r = rsl[h];
        const uint4* p = (const uint4*)(Eb + (size_t)h * 131072 + tid * 16);
        uint4 u0 = p[0], u1 = p[1];
        acc[0] += bf16_lo(u0.x) * r;  acc[1] += bf16_hi(u0.x) * r;
        acc[2] += bf16_lo(u0.y) * r;  acc[3] += bf16_hi(u0.y) * r;
        acc[4] += bf16_lo(u0.z) * r;  acc[5] += bf16_hi(u0.z) * r;
        acc[6] += bf16_lo(u0.w) * r;  acc[7] += bf16_hi(u0.w) * r;
        acc[8] += bf16_lo(u1.x) * r;  acc[9] += bf16_hi(u1.x) * r;
        acc[10] += bf16_lo(u1.y) * r; acc[11] += bf16_hi(u1.y) * r;
        acc[12] += bf16_lo(u1.z) * r; acc[13] += bf16_hi(u1.z) * r;
        acc[14] += bf16_lo(u1.w) * r; acc[15] += bf16_hi(u1.w) * r;
    }
    uint4 o0, o1;
    o0.x = pk_bf16(acc[0], acc[1]);   o0.y = pk_bf16(acc[2], acc[3]);
    o0.z = pk_bf16(acc[4], acc[5]);   o0.w = pk_bf16(acc[6], acc[7]);
    o1.x = pk_bf16(acc[8], acc[9]);   o1.y = pk_bf16(acc[10], acc[11]);
    o1.z = pk_bf16(acc[12], acc[13]); o1.w = pk_bf16(acc[14], acc[15]);
    uint4* wp = (uint4*)(W + (size_t)(b * 32 + l) * 4096 + tid * 16);
    wp[0] = o0; wp[1] = o1;
}

// ---------------------------------------------------------------------------
// K3: y[g][b][l][c] = sum_{n in g*512..+512} W[b][l][n] * x[b][n][c]
// Single-wave blocks, no LDS/barriers. A-frags: 16B loads from W (L2-hot).
// B-frags: ONE bf16x8 (16B) load from xT per fragment (was 8 scalar + 4 pack).
// grid = 32 b * 12 c-tiles * 8 n-groups = 3072 blocks of 64 (12 waves/CU).
// ---------------------------------------------------------------------------
__global__ __launch_bounds__(64)
void yacc_kernel(const unsigned short* __restrict__ xT, const unsigned short* __restrict__ W,
                 float* __restrict__ yws)
{
    const int bx  = blockIdx.x;
    const int b   = bx / 96;
    const int rem = bx - b * 96;
    const int ct  = rem % 12;
    const int g   = rem / 12;
    const int lane = threadIdx.x;
    const int quad = lane >> 4;
    const int lc   = lane & 15;
    const int c0   = ct * 64;
    const int nb   = g * 512;

    const unsigned short* xTb = xT + (size_t)b * 768 * 4096;
    const unsigned short* Wb  = W + (size_t)b * 32 * 4096;

    f32x4 acc[2][4];
    #pragma unroll
    for (int t = 0; t < 2; ++t)
        #pragma unroll
        for (int s = 0; s < 4; ++s) acc[t][s] = (f32x4){0.f, 0.f, 0.f, 0.f};

    for (int kk = 0; kk < 512; kk += 32) {
        const int n = nb + kk + quad * 8;
        bf16x8 a0 = *(const bf16x8*)&Wb[lc * 4096 + n];
        bf16x8 a1 = *(const bf16x8*)&Wb[(16 + lc) * 4096 + n];
        #pragma unroll
        for (int s = 0; s < 4; ++s) {
            bf16x8 bb = *(const bf16x8*)&xTb[(size_t)(c0 + s * 16 + lc) * 4096 + n];
            acc[0][s] = MFMA16(a0, bb, acc[0][s]);
            acc[1][s] = MFMA16(a1, bb, acc[1][s]);
        }
    }

    float* yp = yws + (size_t)((g * 32 + b) * 32) * 768;
    #pragma unroll
    for (int t = 0; t < 2; ++t)
        #pragma unroll
        for (int s = 0; s < 4; ++s)
            #pragma unroll
            for (int r = 0; r < 4; ++r)
                yp[(t * 16 + quad * 4 + r) * 768 + c0 + s * 16 + lc] = acc[t][s][r];
}

// ---------------------------------------------------------------------------
// K4: out[b, l*24+i] = sum_c (sum_g y[g,b,l,c]) * v_w[l*24+i, c] + v_b
// ---------------------------------------------------------------------------
__global__ __launch_bounds__(256)
void out_kernel(const float* __restrict__ yws, const float* __restrict__ vw,
                const float* __restrict__ vb, float* __restrict__ out)
{
    const int b = blockIdx.x >> 5;
    const int l = blockIdx.x & 31;
    const int tid = threadIdx.x;
    __shared__ float y_lds[768];
    for (int c = tid; c < 768; c += 256) {
        float v = 0.f;
        #pragma unroll
        for (int g = 0; g < 8; ++g)
            v += yws[(size_t)((g * 32 + b) * 32 + l) * 768 + c];
        y_lds[c] = v;
    }
    __syncthreads();
    const int wv = tid >> 6, lane = tid & 63;
    for (int i = wv; i < 24; i += 4) {
        const int row = l * 24 + i;
        const float* wr = vw + row * 768;
        float p = 0.f;
        #pragma unroll
        for (int j = 0; j < 12; ++j)
            p += y_lds[j * 64 + lane] * wr[j * 64 + lane];
        #pragma unroll
        for (int m = 1; m < 64; m <<= 1) p += __shfl_xor(p, m);
        if (lane == 0) out[b * 768 + row] = p + vb[row];
    }
}

// ---------------------------------------------------------------------------
extern "C" void kernel_launch(void* const* d_in, const int* in_sizes, int n_in,
                              void* d_out, int out_size, void* d_ws, size_t ws_size,
                              hipStream_t stream)
{
    const float* x      = (const float*)d_in[0];  // [32,4096,768]
    const float* latent = (const float*)d_in[1];  // [1,32,768]
    const float* vw     = (const float*)d_in[2];  // [768,768]
    const float* vb     = (const float*)d_in[3];  // [768]
    float* out = (float*)d_out;                   // [32,768]

    // ws layout (~336 MB; ws_size ~1.6 GB):
    //   [0, 100663296)              E    bf16[32][12][32][4096]
    //   [100663296, 109051904)      W    bf16[32][32][4096]
    //   [109051904, 134217728)      y    f32[8][32][32][768]
    //   [134217728, 335544320)      xT   bf16[32][768][4096]
    //   [335544320, 335593472)      qbf  bf16[12][32][64]
    char* ws = (char*)d_ws;
    unsigned short* E   = (unsigned short*)ws;
    unsigned short* W   = (unsigned short*)(ws + 100663296);
    float*          yws = (float*)(ws + 109051904);
    unsigned short* xT  = (unsigned short*)(ws + 134217728);
    unsigned short* qbf = (unsigned short*)(ws + 335544320);

    k0_qconv<<<dim3(96), dim3(256), 0, stream>>>(latent, qbf);
    k1_logits<<<dim3(2048), dim3(256), 0, stream>>>(x, qbf, E, xT);
    kw_weights<<<dim3(1024), dim3(256), 0, stream>>>(E, W);
    yacc_kernel<<<dim3(3072), dim3(64), 0, stream>>>(xT, W, yws);
    out_kernel<<<dim3(1024), dim3(256), 0, stream>>>(yws, vw, vb, out);
}

// Round 2
// 763.667 us; speedup vs baseline: 1.0216x; 1.0216x over previous
//
#include <hip/hip_runtime.h>
#include <cstdint>

// Problem: B=32, N=4096, C=768, H=12, hd=64, L=32, chunk=24
// Identity: out[b,l,c'] = (sum_n attn[b,l,n] x[b,n,:]) . v_w[l*24+c',:] + v_b
// Pipeline (x read once in f32, once in bf16-transposed form):
//   k0:  qbf = bf16(latent * 0.125); zero sums
//   K1:  per (b, 64-row n-tile, 4-head third): stage x slice ONCE in LDS,
//        then per h: S = qbf . k via MFMA; E=exp(S) -> bf16 (truncated);
//        row-sums of truncated E reduced in-wave -> atomicAdd to sums;
//        xT[b][c][n] bf16 (201 MB) written via LDS transpose.
//        Only 2 barriers per block (was 24) -> stores fire-and-forget.
//   KW:  per (b,l): rs[h] = 1/(12*sums); W[b,l,n] = sum_h E*rs (1 E pass)
//   K3:  y[g][b,l,c] = sum_{n in g} W[b,l,n]*x[b,n,c]  (MFMA, xT vectorized)
//   K4:  out = (sum_g y) . v_w^T + v_b

typedef short bf16x8 __attribute__((ext_vector_type(8)));
typedef float f32x4 __attribute__((ext_vector_type(4)));

#define MFMA16(a, b, c) __builtin_amdgcn_mfma_f32_16x16x32_bf16((a), (b), (c), 0, 0, 0)

// pack two f32 -> (bf16(a) | bf16(b)<<16) by byte-select (truncation, 1 VALU)
__device__ __forceinline__ uint32_t pk_bf16(float a, float b) {
    return __builtin_amdgcn_perm(__float_as_uint(b), __float_as_uint(a), 0x07060302u);
}
__device__ __forceinline__ unsigned short bf16_trunc(float f) {
    return (unsigned short)(__float_as_uint(f) >> 16);
}
__device__ __forceinline__ float bf16_lo(uint32_t u) { return __uint_as_float(u << 16); }
__device__ __forceinline__ float bf16_hi(uint32_t u) { return __uint_as_float(u & 0xffff0000u); }

// ---------------------------------------------------------------------------
// k0: qbf[h][l][d] = bf16(latent[l][h*64+d] * 0.125) (24576 elems); zero sums.
// ---------------------------------------------------------------------------
__global__ __launch_bounds__(256)
void k0_init(const float* __restrict__ latent, unsigned short* __restrict__ qbf,
             float* __restrict__ sums)
{
    int i = blockIdx.x * 256 + threadIdx.x;       // 0..24575
    if (i < 12288) sums[i] = 0.f;
    int l = i / 768;
    int r = i - l * 768;
    int h = r >> 6, d = r & 63;
    qbf[(h * 32 + l) * 64 + d] = bf16_trunc(latent[i] * 0.125f);
}

// ---------------------------------------------------------------------------
// K1: block = (b, 64-row n-tile, head-third hb). Stage x[n0..n0+64][hb*256..+256]
// as bf16 in LDS once (39 KB -> 4 blocks/CU). Then for each of 4 heads:
// MFMA 16x16x32 (A[m=lane&15][k=quad*8+j], B[k][n=lane&15], D col=lane&15,
// row=quad*4+reg); E = exp(S) truncated to bf16, stored + row-summed
// (shfl_xor over the 16-lane quad = n-cols); xT transpose-written from LDS.
// No barriers inside the h loop: stores are never vmcnt(0)-drained mid-block.
// grid = 32*64*3 = 6144 blocks x 256.
// ---------------------------------------------------------------------------
__global__ __launch_bounds__(256)
void k1_logits(const float* __restrict__ x, const unsigned short* __restrict__ qbf,
               unsigned short* __restrict__ E, unsigned short* __restrict__ xT,
               float* __restrict__ sums)
{
    const int bx  = blockIdx.x;
    const int b   = bx >> 7;            // 0..31
    const int r7  = bx & 127;
    const int n0  = (r7 >> 1 >> 0) << 6;  // careful: layout below
    // decode: r7 = ntile*2... we need 64 ntiles x 3 hb. Use: ntile = r7 via
    // grid 32*192: b = bx/192; rem = bx%192; ntile = rem>>2.. simpler below.
    (void)n0;
    const int b2   = bx / 192;
    const int rem  = bx - b2 * 192;
    const int nt   = rem >> 2;          // 0..47?? NO
    (void)b2; (void)nt;
    // Final decode (used): bx = ((b*3 + hb)*64 + ntile)
    const int ntile = bx & 63;
    const int bh    = bx >> 6;          // 0..95
    const int hb    = bh % 3;           // head-third: heads hb*4..hb*4+3
    const int bb    = bh / 3;           // batch
    const int nn0   = ntile << 6;

    const int tid  = threadIdx.x;
    const int wv   = tid >> 6;
    const int lane = tid & 63;
    const int quad = lane >> 4;
    const int lc   = lane & 15;

    __shared__ __align__(16) unsigned short x_lds[4][64][72];  // 36.9 KB
    __shared__ float bsum[4][32][4];                            // 2 KB

    // ---- stage: 64 n x 256 c (4 head-slices), f32 -> bf16, one pass ----
    for (int i = tid; i < 4096; i += 256) {
        const int nn = i >> 6;          // 0..63
        const int j  = i & 63;          // f4 index within 256-col slice
        const int h  = j >> 4, f4 = j & 15;
        float4 xv = *(const float4*)&x[(size_t)(bb * 4096 + nn0 + nn) * 768 + hb * 256 + j * 4];
        uint2 p;
        p.x = pk_bf16(xv.x, xv.y);
        p.y = pk_bf16(xv.z, xv.w);
        *(uint2*)&x_lds[h][nn][f4 * 4] = p;
    }
    __syncthreads();

    const int n  = nn0 + wv * 16 + lc;
    const int td = lane;                // transpose: lanes sweep d

    #pragma unroll
    for (int h = 0; h < 4; ++h) {
        const int hg = hb * 4 + h;
        // A-frags straight from global qbf (L1-hot, 4 KB per head)
        const unsigned short* qh = qbf + hg * 2048;
        bf16x8 a00 = *(const bf16x8*)&qh[lc * 64 + quad * 8];
        bf16x8 a01 = *(const bf16x8*)&qh[lc * 64 + 32 + quad * 8];
        bf16x8 a10 = *(const bf16x8*)&qh[(16 + lc) * 64 + quad * 8];
        bf16x8 a11 = *(const bf16x8*)&qh[(16 + lc) * 64 + 32 + quad * 8];
        bf16x8 b0  = *(const bf16x8*)&x_lds[h][wv * 16 + lc][quad * 8];
        bf16x8 b1  = *(const bf16x8*)&x_lds[h][wv * 16 + lc][32 + quad * 8];

        f32x4 c0 = {0.f, 0.f, 0.f, 0.f};
        f32x4 c1 = {0.f, 0.f, 0.f, 0.f};
        c0 = MFMA16(a00, b0, c0);
        c0 = MFMA16(a01, b1, c0);
        c1 = MFMA16(a10, b0, c1);
        c1 = MFMA16(a11, b1, c1);

        // E = exp(S) truncated; sum the TRUNCATED value so KW's denominators
        // match the stored numerators exactly (same math as old 2-pass KW).
        unsigned short* Eh = E + (size_t)((bb * 12 + hg) * 32) * 4096;
        float sv[8];
        #pragma unroll
        for (int r = 0; r < 4; ++r) {
            // |S| <~ 0.2: exp without max-subtraction is exact softmax math
            uint32_t u0 = __float_as_uint(__expf(c0[r]));
            uint32_t u1 = __float_as_uint(__expf(c1[r]));
            Eh[(quad * 4 + r) * 4096 + n]      = (unsigned short)(u0 >> 16);
            Eh[(16 + quad * 4 + r) * 4096 + n] = (unsigned short)(u1 >> 16);
            sv[r]     = __uint_as_float(u0 & 0xffff0000u);
            sv[4 + r] = __uint_as_float(u1 & 0xffff0000u);
        }
        // reduce over the 16 n-cols of this quad (xor masks 1,2,4,8 stay in-quad)
        #pragma unroll
        for (int m = 1; m < 16; m <<= 1) {
            #pragma unroll
            for (int k = 0; k < 8; ++k) sv[k] += __shfl_xor(sv[k], m);
        }
        if (lc == 0) {
            #pragma unroll
            for (int r = 0; r < 4; ++r) {
                bsum[h][quad * 4 + r][wv]      = sv[r];
                bsum[h][16 + quad * 4 + r][wv] = sv[4 + r];
            }
        }

        // xT write: row = bb*768 + hg*64 + td, cols nn0..nn0+64.
        // LDS read x_lds[h][row][td]: 64 lanes -> 32 consecutive dwords,
        // 2 lanes/dword broadcast -> conflict-free.
        unsigned short* xTrow = xT + ((size_t)bb * 768 + hg * 64 + td) * 4096 + nn0;
        #pragma unroll
        for (int half = 0; half < 2; ++half) {
            const int nc = wv + half * 4;      // n-chunk of 8
            unsigned short r0 = x_lds[h][nc * 8 + 0][td], r1 = x_lds[h][nc * 8 + 1][td];
            unsigned short r2 = x_lds[h][nc * 8 + 2][td], r3 = x_lds[h][nc * 8 + 3][td];
            unsigned short r4 = x_lds[h][nc * 8 + 4][td], r5 = x_lds[h][nc * 8 + 5][td];
            unsigned short r6 = x_lds[h][nc * 8 + 6][td], r7 = x_lds[h][nc * 8 + 7][td];
            uint4 w;
            w.x = (uint32_t)r0 | ((uint32_t)r1 << 16);
            w.y = (uint32_t)r2 | ((uint32_t)r3 << 16);
            w.z = (uint32_t)r4 | ((uint32_t)r5 << 16);
            w.w = (uint32_t)r6 | ((uint32_t)r7 << 16);
            *(uint4*)&xTrow[nc * 8] = w;
        }
    }

    __syncthreads();
    if (tid < 128) {
        const int h = tid >> 5, l = tid & 31;
        atomicAdd(&sums[(bb * 12 + hb * 4 + h) * 32 + l],
                  bsum[h][l][0] + bsum[h][l][1] + bsum[h][l][2] + bsum[h][l][3]);
    }
}

// ---------------------------------------------------------------------------
// KW: block = (b,l), 256 thr. rs[h] from precomputed sums (K1 atomics);
// single E pass: W[b,l,n] = sum_h E * 1/(12*sums[h]). No atomics here.
// ---------------------------------------------------------------------------
__global__ __launch_bounds__(256)
void kw_weights(const unsigned short* __restrict__ E, const float* __restrict__ sums,
                unsigned short* __restrict__ W)
{
    const int b = blockIdx.x >> 5;
    const int l = blockIdx.x & 31;
    const int tid = threadIdx.x;

    const unsigned short* Eb = E + (size_t)(b * 384 + l) * 4096;  // +h*32*4096
    __shared__ float rsl[12];
    if (tid < 12) rsl[tid] = 1.0f / (12.0f * sums[(b * 12 + tid) * 32 + l]);
    __syncthreads();

    float acc[16];
    #pragma unroll
    for (int i = 0; i < 16; ++i) acc[i] = 0.f;
    #pragma unroll
    for (int h = 0; h < 12; ++h) {
        float r = rsl[h];
        const uint4* p = (const uint4*)(Eb + (size_t)h * 131072 + tid * 16);
        uint4 u0 = p[0], u1 = p[1];
        acc[0] += bf16_lo(u0.x) * r;  acc[1] += bf16_hi(u0.x) * r;
        acc[2] += bf16_lo(u0.y) * r;  acc[3] += bf16_hi(u0.y) * r;
        acc[4] += bf16_lo(u0.z) * r;  acc[5] += bf16_hi(u0.z) * r;
        acc[6] += bf16_lo(u0.w) * r;  acc[7] += bf16_hi(u0.w) * r;
        acc[8] += bf16_lo(u1.x) * r;  acc[9] += bf16_hi(u1.x) * r;
        acc[10] += bf16_lo(u1.y) * r; acc[11] += bf16_hi(u1.y) * r;
        acc[12] += bf16_lo(u1.z) * r; acc[13] += bf16_hi(u1.z) * r;
        acc[14] += bf16_lo(u1.w) * r; acc[15] += bf16_hi(u1.w) * r;
    }
    uint4 o0, o1;
    o0.x = pk_bf16(acc[0], acc[1]);   o0.y = pk_bf16(acc[2], acc[3]);
    o0.z = pk_bf16(acc[4], acc[5]);   o0.w = pk_bf16(acc[6], acc[7]);
    o1.x = pk_bf16(acc[8], acc[9]);   o1.y = pk_bf16(acc[10], acc[11]);
    o1.z = pk_bf16(acc[12], acc[13]); o1.w = pk_bf16(acc[14], acc[15]);
    uint4* wp = (uint4*)(W + (size_t)(b * 32 + l) * 4096 + tid * 16);
    wp[0] = o0; wp[1] = o1;
}

// ---------------------------------------------------------------------------
// K3: y[g][b][l][c] = sum_{n in g*512..+512} W[b][l][n] * x[b][n][c]
// Single-wave blocks, no LDS/barriers. A-frags: 16B loads from W (L2-hot).
// B-frags: ONE bf16x8 (16B) load from xT per fragment.
// grid = 32 b * 12 c-tiles * 8 n-groups = 3072 blocks of 64 (12 waves/CU).
// ---------------------------------------------------------------------------
__global__ __launch_bounds__(64)
void yacc_kernel(const unsigned short* __restrict__ xT, const unsigned short* __restrict__ W,
                 float* __restrict__ yws)
{
    const int bx  = blockIdx.x;
    const int b   = bx / 96;
    const int rem = bx - b * 96;
    const int ct  = rem % 12;
    const int g   = rem / 12;
    const int lane = threadIdx.x;
    const int quad = lane >> 4;
    const int lc   = lane & 15;
    const int c0   = ct * 64;
    const int nb   = g * 512;

    const unsigned short* xTb = xT + (size_t)b * 768 * 4096;
    const unsigned short* Wb  = W + (size_t)b * 32 * 4096;

    f32x4 acc[2][4];
    #pragma unroll
    for (int t = 0; t < 2; ++t)
        #pragma unroll
        for (int s = 0; s < 4; ++s) acc[t][s] = (f32x4){0.f, 0.f, 0.f, 0.f};

    for (int kk = 0; kk < 512; kk += 32) {
        const int n = nb + kk + quad * 8;
        bf16x8 a0 = *(const bf16x8*)&Wb[lc * 4096 + n];
        bf16x8 a1 = *(const bf16x8*)&Wb[(16 + lc) * 4096 + n];
        #pragma unroll
        for (int s = 0; s < 4; ++s) {
            bf16x8 bb = *(const bf16x8*)&xTb[(size_t)(c0 + s * 16 + lc) * 4096 + n];
            acc[0][s] = MFMA16(a0, bb, acc[0][s]);
            acc[1][s] = MFMA16(a1, bb, acc[1][s]);
        }
    }

    float* yp = yws + (size_t)((g * 32 + b) * 32) * 768;
    #pragma unroll
    for (int t = 0; t < 2; ++t)
        #pragma unroll
        for (int s = 0; s < 4; ++s)
            #pragma unroll
            for (int r = 0; r < 4; ++r)
                yp[(t * 16 + quad * 4 + r) * 768 + c0 + s * 16 + lc] = acc[t][s][r];
}

// ---------------------------------------------------------------------------
// K4: out[b, l*24+i] = sum_c (sum_g y[g,b,l,c]) * v_w[l*24+i, c] + v_b
// ---------------------------------------------------------------------------
__global__ __launch_bounds__(256)
void out_kernel(const float* __restrict__ yws, const float* __restrict__ vw,
                const float* __restrict__ vb, float* __restrict__ out)
{
    const int b = blockIdx.x >> 5;
    const int l = blockIdx.x & 31;
    const int tid = threadIdx.x;
    __shared__ float y_lds[768];
    for (int c = tid; c < 768; c += 256) {
        float v = 0.f;
        #pragma unroll
        for (int g = 0; g < 8; ++g)
            v += yws[(size_t)((g * 32 + b) * 32 + l) * 768 + c];
        y_lds[c] = v;
    }
    __syncthreads();
    const int wv = tid >> 6, lane = tid & 63;
    for (int i = wv; i < 24; i += 4) {
        const int row = l * 24 + i;
        const float* wr = vw + row * 768;
        float p = 0.f;
        #pragma unroll
        for (int j = 0; j < 12; ++j)
            p += y_lds[j * 64 + lane] * wr[j * 64 + lane];
        #pragma unroll
        for (int m = 1; m < 64; m <<= 1) p += __shfl_xor(p, m);
        if (lane == 0) out[b * 768 + row] = p + vb[row];
    }
}

// ---------------------------------------------------------------------------
extern "C" void kernel_launch(void* const* d_in, const int* in_sizes, int n_in,
                              void* d_out, int out_size, void* d_ws, size_t ws_size,
                              hipStream_t stream)
{
    const float* x      = (const float*)d_in[0];  // [32,4096,768]
    const float* latent = (const float*)d_in[1];  // [1,32,768]
    const float* vw     = (const float*)d_in[2];  // [768,768]
    const float* vb     = (const float*)d_in[3];  // [768]
    float* out = (float*)d_out;                   // [32,768]

    // ws layout (~336 MB; ws_size ~1.6 GB):
    //   [0, 100663296)              E    bf16[32][12][32][4096]
    //   [100663296, 109051904)      W    bf16[32][32][4096]
    //   [109051904, 134217728)      y    f32[8][32][32][768]
    //   [134217728, 335544320)      xT   bf16[32][768][4096]
    //   [335544320, +49152)         qbf  bf16[12][32][64]
    //   [335609856, +49152)         sums f32[32][12][32]
    char* ws = (char*)d_ws;
    unsigned short* E    = (unsigned short*)ws;
    unsigned short* W    = (unsigned short*)(ws + 100663296);
    float*          yws  = (float*)(ws + 109051904);
    unsigned short* xT   = (unsigned short*)(ws + 134217728);
    unsigned short* qbf  = (unsigned short*)(ws + 335544320);
    float*          sums = (float*)(ws + 335609856);

    k0_init<<<dim3(96), dim3(256), 0, stream>>>(latent, qbf, sums);
    k1_logits<<<dim3(6144), dim3(256), 0, stream>>>(x, qbf, E, xT, sums);
    kw_weights<<<dim3(1024), dim3(256), 0, stream>>>(E, sums, W);
    yacc_kernel<<<dim3(3072), dim3(64), 0, stream>>>(xT, W, yws);
    out_kernel<<<dim3(1024), dim3(256), 0, stream>>>(yws, vw, vb, out);
}

// Round 3
// 738.018 us; speedup vs baseline: 1.0571x; 1.0348x over previous
//
#include <hip/hip_runtime.h>
#include <cstdint>

// Problem: B=32, N=4096, C=768, H=12, hd=64, L=32, chunk=24
// Identity: out[b,l,c'] = (sum_n attn[b,l,n] x[b,n,:]) . v_w[l*24+c',:] + v_b
// Pipeline:
//   k0:  qbf = bf16(latent * 0.125); zero sums
//   K1:  per (b, 64-row n-tile, 4-head third): stage x slice in LDS (bf16),
//        FUSED coalesced write of x_bf16[b][n][c] (201 MB, 512B chunks);
//        per h: S = qbf . k via MFMA; E=exp(S) -> bf16; row-sums -> atomics.
//   KW:  per (b,l): rs[h] = 1/(12*sums); W[b,l,n] = sum_h E*rs (1 E pass)
//   K3:  proper 4-wave LDS-staged GEMM: y[kg][b,l,c] = sum_n W[b,l,n]*xbf[b,n,c]
//   K4:  out = (sum_g y) . v_w^T + v_b

typedef short bf16x8 __attribute__((ext_vector_type(8)));
typedef float f32x4 __attribute__((ext_vector_type(4)));

#define MFMA16(a, b, c) __builtin_amdgcn_mfma_f32_16x16x32_bf16((a), (b), (c), 0, 0, 0)

// pack two f32 -> (bf16(a) | bf16(b)<<16) by byte-select (truncation, 1 VALU)
__device__ __forceinline__ uint32_t pk_bf16(float a, float b) {
    return __builtin_amdgcn_perm(__float_as_uint(b), __float_as_uint(a), 0x07060302u);
}
__device__ __forceinline__ unsigned short bf16_trunc(float f) {
    return (unsigned short)(__float_as_uint(f) >> 16);
}
__device__ __forceinline__ float bf16_lo(uint32_t u) { return __uint_as_float(u << 16); }
__device__ __forceinline__ float bf16_hi(uint32_t u) { return __uint_as_float(u & 0xffff0000u); }

// ---------------------------------------------------------------------------
// k0: qbf[h][l][d] = bf16(latent[l][h*64+d] * 0.125) (24576 elems); zero sums.
// ---------------------------------------------------------------------------
__global__ __launch_bounds__(256)
void k0_init(const float* __restrict__ latent, unsigned short* __restrict__ qbf,
             float* __restrict__ sums)
{
    int i = blockIdx.x * 256 + threadIdx.x;       // 0..24575
    if (i < 12288) sums[i] = 0.f;
    int l = i / 768;
    int r = i - l * 768;
    int h = r >> 6, d = r & 63;
    qbf[(h * 32 + l) * 64 + d] = bf16_trunc(latent[i] * 0.125f);
}

// ---------------------------------------------------------------------------
// K1: block = (b, 64-row n-tile, head-third hb). Stage x[64 n][256 c] as bf16
// in LDS once; the SAME packed registers are stored coalesced (512 B/instr)
// to x_bf16[b][n][c]. Then 4 heads: MFMA 16x16x32 (A[m=lane&15][k=quad*8+j],
// B[k][n=lane&15], D col=lane&15, row=quad*4+reg); E = exp(S) bf16-truncated,
// stored + row-summed (quad shfl_xor -> DPP); block sums -> one atomicAdd.
// grid = 32*3*64 = 6144 blocks x 256.
// ---------------------------------------------------------------------------
__global__ __launch_bounds__(256)
void k1_logits(const float* __restrict__ x, const unsigned short* __restrict__ qbf,
               unsigned short* __restrict__ E, unsigned short* __restrict__ xbf,
               float* __restrict__ sums)
{
    const int bx    = blockIdx.x;       // ((b*3 + hb)*64 + ntile)
    const int ntile = bx & 63;
    const int bh    = bx >> 6;          // 0..95
    const int hb    = bh % 3;           // head-third: heads hb*4..hb*4+3
    const int bb    = bh / 3;           // batch
    const int nn0   = ntile << 6;

    const int tid  = threadIdx.x;
    const int wv   = tid >> 6;
    const int lane = tid & 63;
    const int quad = lane >> 4;
    const int lc   = lane & 15;

    __shared__ __align__(16) unsigned short x_lds[4][64][72];  // 36.9 KB
    __shared__ float bsum[4][32][4];                            // 2 KB

    // ---- stage: 64 n x 256 c (4 head-slices), f32 -> bf16, one pass.
    // Fused coalesced x_bf16 write: per instr 64 lanes x 8 B = 512 B chunk.
    for (int i = tid; i < 4096; i += 256) {
        const int nn = i >> 6;          // 0..63
        const int j  = i & 63;          // f4 index within 256-col slice
        const int h  = j >> 4, f4 = j & 15;
        const size_t gof = (size_t)(bb * 4096 + nn0 + nn) * 768 + hb * 256 + j * 4;
        float4 xv = *(const float4*)&x[gof];
        uint2 p;
        p.x = pk_bf16(xv.x, xv.y);
        p.y = pk_bf16(xv.z, xv.w);
        *(uint2*)&x_lds[h][nn][f4 * 4] = p;
        *(uint2*)&xbf[gof] = p;
    }
    __syncthreads();

    const int n = nn0 + wv * 16 + lc;

    #pragma unroll
    for (int h = 0; h < 4; ++h) {
        const int hg = hb * 4 + h;
        // A-frags straight from global qbf (L1-hot, 4 KB per head)
        const unsigned short* qh = qbf + hg * 2048;
        bf16x8 a00 = *(const bf16x8*)&qh[lc * 64 + quad * 8];
        bf16x8 a01 = *(const bf16x8*)&qh[lc * 64 + 32 + quad * 8];
        bf16x8 a10 = *(const bf16x8*)&qh[(16 + lc) * 64 + quad * 8];
        bf16x8 a11 = *(const bf16x8*)&qh[(16 + lc) * 64 + 32 + quad * 8];
        bf16x8 b0  = *(const bf16x8*)&x_lds[h][wv * 16 + lc][quad * 8];
        bf16x8 b1  = *(const bf16x8*)&x_lds[h][wv * 16 + lc][32 + quad * 8];

        f32x4 c0 = {0.f, 0.f, 0.f, 0.f};
        f32x4 c1 = {0.f, 0.f, 0.f, 0.f};
        c0 = MFMA16(a00, b0, c0);
        c0 = MFMA16(a01, b1, c0);
        c1 = MFMA16(a10, b0, c1);
        c1 = MFMA16(a11, b1, c1);

        // E = exp(S) truncated; sum the TRUNCATED value so KW's denominators
        // match the stored numerators exactly.
        unsigned short* Eh = E + (size_t)((bb * 12 + hg) * 32) * 4096;
        float sv[8];
        #pragma unroll
        for (int r = 0; r < 4; ++r) {
            // |S| <~ 0.2: exp without max-subtraction is exact softmax math
            uint32_t u0 = __float_as_uint(__expf(c0[r]));
            uint32_t u1 = __float_as_uint(__expf(c1[r]));
            Eh[(quad * 4 + r) * 4096 + n]      = (unsigned short)(u0 >> 16);
            Eh[(16 + quad * 4 + r) * 4096 + n] = (unsigned short)(u1 >> 16);
            sv[r]     = __uint_as_float(u0 & 0xffff0000u);
            sv[4 + r] = __uint_as_float(u1 & 0xffff0000u);
        }
        // reduce over the 16 n-cols of this quad (masks 1,2,4,8 stay in-quad)
        #pragma unroll
        for (int m = 1; m < 16; m <<= 1) {
            #pragma unroll
            for (int k = 0; k < 8; ++k) sv[k] += __shfl_xor(sv[k], m);
        }
        if (lc == 0) {
            #pragma unroll
            for (int r = 0; r < 4; ++r) {
                bsum[h][quad * 4 + r][wv]      = sv[r];
                bsum[h][16 + quad * 4 + r][wv] = sv[4 + r];
            }
        }
    }

    __syncthreads();
    if (tid < 128) {
        const int h = tid >> 5, l = tid & 31;
        atomicAdd(&sums[(bb * 12 + hb * 4 + h) * 32 + l],
                  bsum[h][l][0] + bsum[h][l][1] + bsum[h][l][2] + bsum[h][l][3]);
    }
}

// ---------------------------------------------------------------------------
// KW: block = (b,l), 256 thr. rs[h] from precomputed sums (K1 atomics);
// single E pass: W[b,l,n] = sum_h E * 1/(12*sums[h]). No atomics here.
// ---------------------------------------------------------------------------
__global__ __launch_bounds__(256)
void kw_weights(const unsigned short* __restrict__ E, const float* __restrict__ sums,
                unsigned short* __restrict__ W)
{
    const int b = blockIdx.x >> 5;
    const int l = blockIdx.x & 31;
    const int tid = threadIdx.x;

    const unsigned short* Eb = E + (size_t)(b * 384 + l) * 4096;  // +h*32*4096
    __shared__ float rsl[12];
    if (tid < 12) rsl[tid] = 1.0f / (12.0f * sums[(b * 12 + tid) * 32 + l]);
    __syncthreads();

    float acc[16];
    #pragma unroll
    for (int i = 0; i < 16; ++i) acc[i] = 0.f;
    #pragma unroll
    for (int h = 0; h < 12; ++h) {
        float r = rsl[h];
        const uint4* p = (const uint4*)(Eb + (size_t)h * 131072 + tid * 16);
        uint4 u0 = p[0], u1 = p[1];
        acc[0] += bf16_lo(u0.x) * r;  acc[1] += bf16_hi(u0.x) * r;
        acc[2] += bf16_lo(u0.y) * r;  acc[3] += bf16_hi(u0.y) * r;
        acc[4] += bf16_lo(u0.z) * r;  acc[5] += bf16_hi(u0.z) * r;
        acc[6] += bf16_lo(u0.w) * r;  acc[7] += bf16_hi(u0.w) * r;
        acc[8] += bf16_lo(u1.x) * r;  acc[9] += bf16_hi(u1.x) * r;
        acc[10] += bf16_lo(u1.y) * r; acc[11] += bf16_hi(u1.y) * r;
        acc[12] += bf16_lo(u1.z) * r; acc[13] += bf16_hi(u1.z) * r;
        acc[14] += bf16_lo(u1.w) * r; acc[15] += bf16_hi(u1.w) * r;
    }
    uint4 o0, o1;
    o0.x = pk_bf16(acc[0], acc[1]);   o0.y = pk_bf16(acc[2], acc[3]);
    o0.z = pk_bf16(acc[4], acc[5]);   o0.w = pk_bf16(acc[6], acc[7]);
    o1.x = pk_bf16(acc[8], acc[9]);   o1.y = pk_bf16(acc[10], acc[11]);
    o1.z = pk_bf16(acc[12], acc[13]); o1.w = pk_bf16(acc[14], acc[15]);
    uint4* wp = (uint4*)(W + (size_t)(b * 32 + l) * 4096 + tid * 16);
    wp[0] = o0; wp[1] = o1;
}

// ---------------------------------------------------------------------------
// K3: LDS-staged GEMM. block = (b, cn, kg): y[kg][b][l][c0..c0+128] =
// sum_{n in kg*512..+512} W[b][l][n] * xbf[b][n][c].
// Per BK=64 iter: stage W[32][64] (4 KB, pad 72) + x[64][128] (16 KB, pad 130:
// u16 column-gathers hit banks 8*quad + lc/2 + j -> all 32, conflict-free).
// Loads issued BEFORE barrier (latency hides under prev iter's MFMA).
// A-frags: ds_read_b128 from wl. B-frags: 8x ds_read_u16 + 4 shifts.
// grid = 32*6*8 = 1536 blocks x 256 (4 waves; wave owns 32 c). 6 blocks/CU.
// ---------------------------------------------------------------------------
__global__ __launch_bounds__(256)
void yacc_kernel(const unsigned short* __restrict__ xbf, const unsigned short* __restrict__ W,
                 float* __restrict__ yws)
{
    const int bx = blockIdx.x;          // ((b*6 + cn)*8 + kg)
    const int kg = bx & 7;
    const int bc = bx >> 3;
    const int cn = bc % 6;
    const int b  = bc / 6;
    const int c0 = cn * 128;
    const int n00 = kg * 512;

    const int tid  = threadIdx.x;
    const int wv   = tid >> 6;
    const int lane = tid & 63;
    const int quad = lane >> 4;
    const int lc   = lane & 15;

    __shared__ __align__(16) unsigned short wl[32][72];    // 4.6 KB
    __shared__ __align__(16) unsigned short xl[64][130];   // 16.6 KB

    const unsigned short* Wb = W + (size_t)b * 32 * 4096;
    const unsigned short* xb = xbf + (size_t)b * 4096 * 768;

    f32x4 acc[2][2];
    #pragma unroll
    for (int t = 0; t < 2; ++t)
        #pragma unroll
        for (int cs = 0; cs < 2; ++cs) acc[t][cs] = (f32x4){0.f, 0.f, 0.f, 0.f};

    const int wrow = tid >> 3, wchk = tid & 7;   // W stage: 8 lanes/row -> full lines

    for (int it = 0; it < 8; ++it) {
        const int n0 = n00 + it * 64;
        // ---- issue global loads early ----
        uint4 wreg = *(const uint4*)&Wb[(size_t)wrow * 4096 + n0 + wchk * 8];
        uint4 xreg[4];
        #pragma unroll
        for (int k = 0; k < 4; ++k) {
            const int m = tid + k * 256;
            xreg[k] = *(const uint4*)&xb[(size_t)(n0 + (m >> 4)) * 768 + c0 + (m & 15) * 8];
        }
        __syncthreads();   // prev iter's LDS reads complete before overwrite
        *(uint4*)&wl[wrow][wchk * 8] = wreg;
        #pragma unroll
        for (int k = 0; k < 4; ++k) {
            const int m = tid + k * 256;
            *(uint4*)&xl[m >> 4][(m & 15) * 8] = xreg[k];
        }
        __syncthreads();

        // ---- compute: 2 k-steps x (2 A-frags, 2 B-frags) = 8 MFMA ----
        #pragma unroll
        for (int ks = 0; ks < 2; ++ks) {
            bf16x8 a0 = *(const bf16x8*)&wl[lc][ks * 32 + quad * 8];
            bf16x8 a1 = *(const bf16x8*)&wl[16 + lc][ks * 32 + quad * 8];
            #pragma unroll
            for (int cs = 0; cs < 2; ++cs) {
                const int cc = wv * 32 + cs * 16 + lc;
                const unsigned short* col = &xl[ks * 32 + quad * 8][cc];
                uint32_t e0 = col[0],       e1 = col[130];
                uint32_t e2 = col[2 * 130], e3 = col[3 * 130];
                uint32_t e4 = col[4 * 130], e5 = col[5 * 130];
                uint32_t e6 = col[6 * 130], e7 = col[7 * 130];
                union { uint32_t u[4]; bf16x8 v; } bbu;
                bbu.u[0] = e0 | (e1 << 16);
                bbu.u[1] = e2 | (e3 << 16);
                bbu.u[2] = e4 | (e5 << 16);
                bbu.u[3] = e6 | (e7 << 16);
                acc[0][cs] = MFMA16(a0, bbu.v, acc[0][cs]);
                acc[1][cs] = MFMA16(a1, bbu.v, acc[1][cs]);
            }
        }
    }

    // D col=lane&15 -> c = c0 + wv*32 + cs*16 + lc; row=quad*4+r -> l = t*16+...
    float* yp = yws + (size_t)((kg * 32 + b) * 32) * 768;
    #pragma unroll
    for (int t = 0; t < 2; ++t)
        #pragma unroll
        for (int cs = 0; cs < 2; ++cs)
            #pragma unroll
            for (int r = 0; r < 4; ++r)
                yp[(t * 16 + quad * 4 + r) * 768 + c0 + wv * 32 + cs * 16 + lc] = acc[t][cs][r];
}

// ---------------------------------------------------------------------------
// K4: out[b, l*24+i] = sum_c (sum_g y[g,b,l,c]) * v_w[l*24+i, c] + v_b
// ---------------------------------------------------------------------------
__global__ __launch_bounds__(256)
void out_kernel(const float* __restrict__ yws, const float* __restrict__ vw,
                const float* __restrict__ vb, float* __restrict__ out)
{
    const int b = blockIdx.x >> 5;
    const int l = blockIdx.x & 31;
    const int tid = threadIdx.x;
    __shared__ float y_lds[768];
    for (int c = tid; c < 768; c += 256) {
        float v = 0.f;
        #pragma unroll
        for (int g = 0; g < 8; ++g)
            v += yws[(size_t)((g * 32 + b) * 32 + l) * 768 + c];
        y_lds[c] = v;
    }
    __syncthreads();
    const int wv = tid >> 6, lane = tid & 63;
    for (int i = wv; i < 24; i += 4) {
        const int row = l * 24 + i;
        const float* wr = vw + row * 768;
        float p = 0.f;
        #pragma unroll
        for (int j = 0; j < 12; ++j)
            p += y_lds[j * 64 + lane] * wr[j * 64 + lane];
        #pragma unroll
        for (int m = 1; m < 64; m <<= 1) p += __shfl_xor(p, m);
        if (lane == 0) out[b * 768 + row] = p + vb[row];
    }
}

// ---------------------------------------------------------------------------
extern "C" void kernel_launch(void* const* d_in, const int* in_sizes, int n_in,
                              void* d_out, int out_size, void* d_ws, size_t ws_size,
                              hipStream_t stream)
{
    const float* x      = (const float*)d_in[0];  // [32,4096,768]
    const float* latent = (const float*)d_in[1];  // [1,32,768]
    const float* vw     = (const float*)d_in[2];  // [768,768]
    const float* vb     = (const float*)d_in[3];  // [768]
    float* out = (float*)d_out;                   // [32,768]

    // ws layout (~336 MB; ws_size ~1.6 GB):
    //   [0, 100663296)              E    bf16[32][12][32][4096]
    //   [100663296, 109051904)      W    bf16[32][32][4096]
    //   [109051904, 134217728)      y    f32[8][32][32][768]
    //   [134217728, 335544320)      xbf  bf16[32][4096][768]  (natural layout)
    //   [335544320, +49152)         qbf  bf16[12][32][64]
    //   [335609856, +49152)         sums f32[32][12][32]
    char* ws = (char*)d_ws;
    unsigned short* E    = (unsigned short*)ws;
    unsigned short* W    = (unsigned short*)(ws + 100663296);
    float*          yws  = (float*)(ws + 109051904);
    unsigned short* xbf  = (unsigned short*)(ws + 134217728);
    unsigned short* qbf  = (unsigned short*)(ws + 335544320);
    float*          sums = (float*)(ws + 335609856);

    k0_init<<<dim3(96), dim3(256), 0, stream>>>(latent, qbf, sums);
    k1_logits<<<dim3(6144), dim3(256), 0, stream>>>(x, qbf, E, xbf, sums);
    kw_weights<<<dim3(1024), dim3(256), 0, stream>>>(E, sums, W);
    yacc_kernel<<<dim3(1536), dim3(256), 0, stream>>>(xbf, W, yws);
    out_kernel<<<dim3(1024), dim3(256), 0, stream>>>(yws, vw, vb, out);
}